// Round 2
// baseline (360.560 us; speedup 1.0000x reference)
//
#include <hip/hip_runtime.h>

#define NN 50000
#define HID 128
#define NE 800000
#define ET (NE + NN)          // edges + self loops
#define NEG_SLOPE 0.2f
#define CAP 64                // padded CSR slots per node (max deg ~45)

typedef __attribute__((ext_vector_type(8))) short short8v;  // 8 bf16 = 4 VGPRs
typedef __attribute__((ext_vector_type(4))) float f32x4;    // MFMA accumulator

__device__ inline float b2f(unsigned short u) {
    union { unsigned int i; float f; } x; x.i = ((unsigned int)u) << 16; return x.f;
}
__device__ inline unsigned short f2b(float f) {
    unsigned int x; __builtin_memcpy(&x, &f, 4);
    unsigned int lsb = (x >> 16) & 1u;
    x += 0x7fffu + lsb;                  // round-to-nearest-even
    return (unsigned short)(x >> 16);
}
// split fp32 into bf16 hi + bf16 lo so that b2f(hi)+b2f(lo) ~= v (rel err ~2^-17)
__device__ inline void splitbf(float v, unsigned short& hi, unsigned short& lo) {
    hi = f2b(v);
    lo = f2b(v - b2f(hi));
}

// ---------- runtime dtype probe ----------
// bf16 z: exponent fields ~[110,130]. fp32 z read as half-words: ~59% wild.
__global__ void probe_dtype(const unsigned short* __restrict__ z, int* __restrict__ flag) {
    if (threadIdx.x != 0 || blockIdx.x != 0) return;
    int wild = 0;
    for (int i = 0; i < 256; i += 2) {
        unsigned short u = z[i];
        int ef = (u >> 7) & 0xFF;
        if (ef >= 0x9A || (ef <= 0x30 && u != 0)) ++wild;
    }
    *flag = (wild < 8) ? 1 : 0;
}

// ---------- param conversion (bf16 OR fp32 -> fp32) ----------
__global__ void cvt_to_f32(const void* __restrict__ in, float* __restrict__ out, int n,
                           const int* __restrict__ flag) {
    int i = blockIdx.x * 256 + threadIdx.x;
    if (i >= n) return;
    if (*flag) out[i] = b2f(((const unsigned short*)in)[i]);
    else       out[i] = ((const float*)in)[i];
}

// ---------- W -> MFMA B-fragment layout, split precision ----------
// Out per layer: [hi: 128 cols x 128 k][lo: 128 cols x 128 k] bf16, k contiguous
// (i.e. W^T with k innermost). Lane's 8-element k-run is then one 16B load.
__global__ void wprep(const void* __restrict__ Ws, unsigned short* __restrict__ Wb,
                      const int* __restrict__ flag) {
    int i = blockIdx.x * 256 + threadIdx.x;       // over 3*128*128
    if (i >= 3 * HID * HID) return;
    int L = i >> 14;
    int k = (i >> 7) & 127;                       // source row of W[L]
    int n = i & 127;                              // source col of W[L]
    float v = *flag ? b2f(((const unsigned short*)Ws)[i]) : ((const float*)Ws)[i];
    unsigned short hi, lo;
    splitbf(v, hi, lo);
    unsigned short* base = Wb + (size_t)L * 2 * HID * HID;
    base[n * HID + k]             = hi;
    base[HID * HID + n * HID + k] = lo;
}

// ---------- padded-CSR scatter, XCD-swizzled ----------
#define SCHUNK 1024
__global__ __launch_bounds__(256) void scatter_padded(
        const int* __restrict__ ei, int* __restrict__ pos, int* __restrict__ csr) {
    const int rng  = blockIdx.x & 7;
    const int base = (blockIdx.x >> 3) * SCHUNK;
#pragma unroll
    for (int k = 0; k < SCHUNK / 256; ++k) {
        int e = base + k * 256 + threadIdx.x;
        if (e >= ET) continue;
        int d = (e < NE) ? ei[NE + e] : (e - NE);
        if ((d * 8) / NN != rng) continue;        // not my dst range
        int s = (e < NE) ? ei[e] : d;
        int slot = atomicAdd(&pos[d], 1);
        if (slot < CAP) csr[(d << 6) + slot] = s;
    }
}

// ---------- MFMA GEMM (x = h@W) + per-node attention logits ----------
// 64 rows/block, 4 waves x 16-row stripes. h staged hi/lo bf16 in LDS
// (XOR-swizzled: [64][128] bf16 read as b128 is a 16-way conflict otherwise).
// Split-precision: AhiBhi + AloBhi + AhiBlo with fp32 accumulate -> fp32-exact x.
// C/D layout (HW-verified): col = lane&15, row = (lane>>4)*4 + reg.
__global__ __launch_bounds__(256) void gemm_alpha(
        const void* __restrict__ h_, const unsigned short* __restrict__ Wb,
        const float* __restrict__ a_s, const float* __restrict__ a_d,
        unsigned short* __restrict__ x, float* __restrict__ alpha_s, float* __restrict__ alpha_d,
        const int* __restrict__ flag) {
    __shared__ unsigned short Ah[64 * HID];   // 16 KB
    __shared__ unsigned short Al[64 * HID];   // 16 KB
    const int t = threadIdx.x;
    const int base = blockIdx.x * 64;
    const int hf = *flag;

    // ---- stage 64x128 h tile as hi/lo bf16, swizzled ----
    // 2048 chunks of 4 elems; thread handles 8 chunks.
#pragma unroll
    for (int i = 0; i < 8; ++i) {
        int c   = i * 256 + t;
        int row = c >> 5;                 // 32 chunks per row
        int col = (c & 31) * 4;
        float4 v = make_float4(0.f, 0.f, 0.f, 0.f);
        int r = base + row;
        if (r < NN) {
            if (hf) {
                ushort4 u = *(const ushort4*)((const unsigned short*)h_ + (size_t)r * HID + col);
                v = make_float4(b2f(u.x), b2f(u.y), b2f(u.z), b2f(u.w));
            } else {
                v = *(const float4*)((const float*)h_ + (size_t)r * HID + col);
            }
        }
        ushort4 hi, lo;
        splitbf(v.x, hi.x, lo.x); splitbf(v.y, hi.y, lo.y);
        splitbf(v.z, hi.z, lo.z); splitbf(v.w, hi.w, lo.w);
        int ba = (row * 256 + col * 2) ^ ((row & 7) << 4);   // byte addr, 8B aligned
        *(ushort4*)((char*)Ah + ba) = hi;
        *(ushort4*)((char*)Al + ba) = lo;
    }
    __syncthreads();

    // ---- MFMA main: each wave owns rows [w*16, w*16+16) x all 128 cols ----
    const int w  = t >> 6;
    const int l  = t & 63;
    const int lr = l & 15;    // A row / B,D col within 16
    const int lk = l >> 4;    // quarter: k sub-block
    const unsigned short* Whi = Wb;
    const unsigned short* Wlo = Wb + HID * HID;

    f32x4 acc[8];
#pragma unroll
    for (int nt = 0; nt < 8; ++nt) acc[nt] = (f32x4){0.f, 0.f, 0.f, 0.f};

    const int arow = w * 16 + lr;
#pragma unroll
    for (int ks = 0; ks < 4; ++ks) {
        int ab = (arow * 256 + ks * 64 + lk * 16) ^ ((arow & 7) << 4);
        short8v ahi = *(const short8v*)((const char*)Ah + ab);
        short8v alo = *(const short8v*)((const char*)Al + ab);
#pragma unroll
        for (int nt = 0; nt < 8; ++nt) {
            int boff = (nt * 16 + lr) * HID + ks * 32 + lk * 8;   // 16B aligned
            short8v bhi = *(const short8v*)(Whi + boff);
            short8v blo = *(const short8v*)(Wlo + boff);
            acc[nt] = __builtin_amdgcn_mfma_f32_16x16x32_bf16(ahi, bhi, acc[nt], 0, 0, 0);
            acc[nt] = __builtin_amdgcn_mfma_f32_16x16x32_bf16(alo, bhi, acc[nt], 0, 0, 0);
            acc[nt] = __builtin_amdgcn_mfma_f32_16x16x32_bf16(ahi, blo, acc[nt], 0, 0, 0);
        }
    }

    // ---- epilogue: alpha logits from fp32 acc, then bf16 x store ----
    float ps[4] = {0.f, 0.f, 0.f, 0.f};
    float pd[4] = {0.f, 0.f, 0.f, 0.f};
#pragma unroll
    for (int nt = 0; nt < 8; ++nt) {
        float asv = a_s[nt * 16 + lr];
        float adv = a_d[nt * 16 + lr];
#pragma unroll
        for (int r = 0; r < 4; ++r) {
            ps[r] = fmaf(acc[nt][r], asv, ps[r]);
            pd[r] = fmaf(acc[nt][r], adv, pd[r]);
        }
    }
#pragma unroll
    for (int m = 8; m >= 1; m >>= 1) {
#pragma unroll
        for (int r = 0; r < 4; ++r) {
            ps[r] += __shfl_xor(ps[r], m, 16);   // reduce across the 16 col-lanes
            pd[r] += __shfl_xor(pd[r], m, 16);
        }
    }
#pragma unroll
    for (int r = 0; r < 4; ++r) {
        int grow = base + w * 16 + lk * 4 + r;
        if (grow < NN) {
#pragma unroll
            for (int nt = 0; nt < 8; ++nt)
                x[(size_t)grow * HID + nt * 16 + lr] = f2b(acc[nt][r]);
            if (lr == 0) { alpha_s[grow] = ps[r]; alpha_d[grow] = pd[r]; }
        }
    }
}

// ---------- fused softmax + weighted aggregation ----------
__global__ __launch_bounds__(256) void aggregate_fused(
        const unsigned short* __restrict__ x, const int* __restrict__ deg_,
        const int* __restrict__ csr, const float* __restrict__ als,
        const float* __restrict__ ald, const float* __restrict__ bias,
        void* __restrict__ out, const int* __restrict__ flag, int do_relu) {
    int node = (blockIdx.x * 256 + threadIdx.x) >> 6;
    int lane = threadIdx.x & 63;
    if (node >= NN) return;
    int deg = min(deg_[node], CAP);
    const int* list = csr + (node << 6);
    const unsigned int* x2 = (const unsigned int*)x;   // ushort2 as u32
    float adv = ald[node];
    float accx = 0.f, accy = 0.f, den = 0.f;
    for (int j0 = 0; j0 < deg; j0 += 8) {
        int idx[8];
#pragma unroll
        for (int k = 0; k < 8; ++k) {
            int j = j0 + k;
            idx[k] = list[j < deg ? j : j0];
        }
        float e8[8];
#pragma unroll
        for (int k = 0; k < 8; ++k) e8[k] = als[idx[k]];        // broadcast gather
        unsigned int u[8];
#pragma unroll
        for (int k = 0; k < 8; ++k) u[k] = x2[(size_t)idx[k] * 64 + lane];
#pragma unroll
        for (int k = 0; k < 8; ++k) {
            float e = e8[k] + adv;
            e = fmaxf(e, NEG_SLOPE * e);             // leaky_relu
            e = fminf(e, 60.f);                      // inf hardening
            float p = (j0 + k < deg) ? __expf(e) : 0.f;
            den += p;
            accx = fmaf(p, b2f((unsigned short)(u[k] & 0xFFFFu)), accx);
            accy = fmaf(p, b2f((unsigned short)(u[k] >> 16)), accy);
        }
    }
    float inv = 1.f / (den + 1e-16f);
    float2 bv = ((const float2*)bias)[lane];
    float ox = accx * inv + bv.x;
    float oy = accy * inv + bv.y;
    if (do_relu) { ox = fmaxf(ox, 0.f); oy = fmaxf(oy, 0.f); }
    if (*flag) {
        ushort2 pk; pk.x = f2b(ox); pk.y = f2b(oy);
        *(ushort2*)((unsigned short*)out + node * HID + lane * 2) = pk;
    } else {
        ((float2*)out)[node * 64 + lane] = make_float2(ox, oy);
    }
}

extern "C" void kernel_launch(void* const* d_in, const int* in_sizes, int n_in,
                              void* d_out, int out_size, void* d_ws, size_t ws_size,
                              hipStream_t stream) {
    const void* z_in  = d_in[0];
    const int*  ei    = (const int*)d_in[1];
    const void* Ws_in = d_in[2];
    const void* as_in = d_in[3];
    const void* ad_in = d_in[4];
    const void* b_in  = d_in[5];

    char* wsp = (char*)d_ws;
    auto alloc = [&](size_t bytes) -> char* {
        char* p = wsp; wsp += (bytes + 255) & ~(size_t)255; return p;
    };
    int*            dflag   = (int*)alloc(4);
    int*            pos     = (int*)alloc(NN * 4);               // degree array
    int*            csrp    = (int*)alloc((size_t)NN * CAP * 4); // padded CSR (12.8 MB)
    float*          alpha_s = (float*)alloc(NN * 4);
    float*          alpha_d = (float*)alloc(NN * 4);
    unsigned short* Wb      = (unsigned short*)alloc((size_t)3 * 2 * HID * HID * 2); // hi/lo W^T bf16
    float*          asf     = (float*)alloc(3 * HID * 4);
    float*          adf     = (float*)alloc(3 * HID * 4);
    float*          bff     = (float*)alloc(3 * HID * 4);
    unsigned short* xb      = (unsigned short*)alloc((size_t)NN * HID * 2);  // bf16 x

    // dtype probe first — everything downstream branches on *dflag
    probe_dtype<<<1, 64, 0, stream>>>((const unsigned short*)z_in, dflag);

    // params: W -> split bf16 fragment layout; vectors -> f32
    wprep<<<(3 * HID * HID + 255) / 256, 256, 0, stream>>>(Ws_in, Wb, dflag);
    cvt_to_f32<<<2, 256, 0, stream>>>(as_in, asf, 3 * HID, dflag);
    cvt_to_f32<<<2, 256, 0, stream>>>(ad_in, adf, 3 * HID, dflag);
    cvt_to_f32<<<2, 256, 0, stream>>>(b_in, bff, 3 * HID, dflag);

    // padded CSR build: memset degrees + single swizzled scatter pass
    hipMemsetAsync(pos, 0, NN * 4, stream);
    const int chunks = (ET + SCHUNK - 1) / SCHUNK;
    scatter_padded<<<chunks * 8, 256, 0, stream>>>(ei, pos, csrp);

    const int gemm_blocks = (NN + 63) / 64;
    const int wave_blocks = (NN + 3) / 4;   // 4 waves (nodes) per 256-thread block
    const size_t WL = 2 * HID * HID;        // per-layer Wb stride (ushorts)

    // layer 0
    gemm_alpha<<<gemm_blocks, 256, 0, stream>>>(z_in, Wb, asf, adf, xb, alpha_s, alpha_d, dflag);
    aggregate_fused<<<wave_blocks, 256, 0, stream>>>(xb, pos, csrp, alpha_s, alpha_d, bff, d_out, dflag, 1);

    // layer 1 (d_out ping-pong: aggregate reads only xb/als/csr — overwrite safe)
    gemm_alpha<<<gemm_blocks, 256, 0, stream>>>(d_out, Wb + WL, asf + HID, adf + HID,
                                                xb, alpha_s, alpha_d, dflag);
    aggregate_fused<<<wave_blocks, 256, 0, stream>>>(xb, pos, csrp, alpha_s, alpha_d, bff + HID, d_out, dflag, 1);

    // layer 2 (final, no relu)
    gemm_alpha<<<gemm_blocks, 256, 0, stream>>>(d_out, Wb + 2 * HID * HID * 2, asf + 2 * HID,
                                                adf + 2 * HID, xb, alpha_s, alpha_d, dflag);
    aggregate_fused<<<wave_blocks, 256, 0, stream>>>(xb, pos, csrp, alpha_s, alpha_d, bff + 2 * HID, d_out, dflag, 0);
}

// Round 3
// 313.190 us; speedup vs baseline: 1.1512x; 1.1512x over previous
//
#include <hip/hip_runtime.h>

#define NN 50000
#define HID 128
#define NE 800000
#define ET (NE + NN)          // edges + self loops
#define NEG_SLOPE 0.2f
#define CAP 64                // padded CSR slots per node (max deg ~45)

typedef __attribute__((ext_vector_type(8))) short short8v;  // 8 bf16 = 4 VGPRs
typedef __attribute__((ext_vector_type(4))) float f32x4;    // MFMA accumulator

__device__ inline float b2f(unsigned short u) {
    union { unsigned int i; float f; } x; x.i = ((unsigned int)u) << 16; return x.f;
}
__device__ inline unsigned short f2b(float f) {
    unsigned int x; __builtin_memcpy(&x, &f, 4);
    unsigned int lsb = (x >> 16) & 1u;
    x += 0x7fffu + lsb;                  // round-to-nearest-even
    return (unsigned short)(x >> 16);
}
// split fp32 into bf16 hi + bf16 lo so that b2f(hi)+b2f(lo) ~= v (rel err ~2^-17)
__device__ inline void splitbf(float v, unsigned short& hi, unsigned short& lo) {
    hi = f2b(v);
    lo = f2b(v - b2f(hi));
}

// ---------- runtime dtype probe (wave-parallel) ----------
// bf16 z: exponent fields ~[110,130]. fp32 z read as half-words: ~59% wild.
// Same 128 even-halfword samples as the serial version, one wave, 2 per lane.
__global__ void probe_dtype(const unsigned short* __restrict__ z, int* __restrict__ flag) {
    int lane = threadIdx.x;                    // 64 threads
    unsigned short a = z[lane * 4];
    unsigned short b = z[lane * 4 + 2];
    int ea = (a >> 7) & 0xFF, eb = (b >> 7) & 0xFF;
    int w1 = (ea >= 0x9A || (ea <= 0x30 && a != 0)) ? 1 : 0;
    int w2 = (eb >= 0x9A || (eb <= 0x30 && b != 0)) ? 1 : 0;
    int wild = __popcll(__ballot(w1)) + __popcll(__ballot(w2));
    if (lane == 0) *flag = (wild < 8) ? 1 : 0;
}

// ---------- param vectors (a_s, a_d, bias) -> fp32, one launch ----------
__global__ void cvt3(const void* __restrict__ a, const void* __restrict__ b,
                     const void* __restrict__ c, float* __restrict__ oa,
                     float* __restrict__ ob, float* __restrict__ oc,
                     const int* __restrict__ flag) {
    int i = blockIdx.x * 256 + threadIdx.x;    // 0..1151
    if (i >= 3 * 3 * HID) return;
    int which = i / (3 * HID), j = i - which * (3 * HID);
    const void* in = which == 0 ? a : which == 1 ? b : c;
    float* out = which == 0 ? oa : which == 1 ? ob : oc;
    out[j] = *flag ? b2f(((const unsigned short*)in)[j]) : ((const float*)in)[j];
}

// ---------- W -> MFMA B-operand, split precision ----------
// Per layer (32768 ushorts): [hi: 32 KB LDS-image, XOR-swizzled, k-contiguous]
//                            [lo: plain W^T, k-contiguous].
// hi is the exact byte image gemm_alpha memcpy's into LDS: element (n,k) at
// byte ((n*256 + 2k) ^ ((n&7)<<4)) — swizzle baked in so the staging copy is
// linear and the LDS read is bank-conflict-free (~2-way max).
__global__ void wprep(const void* __restrict__ Ws, unsigned short* __restrict__ Wb,
                      const int* __restrict__ flag) {
    int i = blockIdx.x * 256 + threadIdx.x;       // over 3*128*128
    if (i >= 3 * HID * HID) return;
    int L = i >> 14;
    int k = (i >> 7) & 127;                       // source row of W[L]
    int n = i & 127;                              // source col of W[L]
    float v = *flag ? b2f(((const unsigned short*)Ws)[i]) : ((const float*)Ws)[i];
    unsigned short hi, lo;
    splitbf(v, hi, lo);
    unsigned short* hbase = Wb + (size_t)L * 2 * HID * HID;   // swizzled hi block
    unsigned short* lbase = hbase + HID * HID;                // plain lo block
    int bo = (n * 256 + k * 2) ^ ((n & 7) << 4);
    *(unsigned short*)((char*)hbase + bo) = hi;
    lbase[n * HID + k] = lo;
}

// ---------- padded-CSR scatter, XCD-swizzled ----------
#define SCHUNK 1024
__global__ __launch_bounds__(256) void scatter_padded(
        const int* __restrict__ ei, int* __restrict__ pos, int* __restrict__ csr) {
    const int rng  = blockIdx.x & 7;
    const int base = (blockIdx.x >> 3) * SCHUNK;
#pragma unroll
    for (int k = 0; k < SCHUNK / 256; ++k) {
        int e = base + k * 256 + threadIdx.x;
        if (e >= ET) continue;
        int d = (e < NE) ? ei[NE + e] : (e - NE);
        if ((d * 8) / NN != rng) continue;        // not my dst range
        int s = (e < NE) ? ei[e] : d;
        int slot = atomicAdd(&pos[d], 1);
        if (slot < CAP) csr[(d << 6) + slot] = s;
    }
}

// ---------- MFMA GEMM (x = h@W) + per-node attention logits, v2 ----------
// A (h rows) -> registers DIRECTLY from global: each wave owns a disjoint
// 16-row stripe, so LDS-staging A was pure overhead (no cross-wave sharing).
// W-hi (shared 8x per wave) staged once into LDS via straight 32-KB copy of
// wprep's pre-swizzled image; W-lo from L2-hot global. One barrier total.
// Split-precision: AhiBhi (+AloBhi if fp32 input) +AhiBlo, fp32 accumulate.
// C/D layout (HW-verified): col = lane&15, row = (lane>>4)*4 + reg.
__global__ __launch_bounds__(256) void gemm_alpha(
        const void* __restrict__ h_, const unsigned short* __restrict__ Wb,
        const float* __restrict__ a_s, const float* __restrict__ a_d,
        unsigned short* __restrict__ x, float* __restrict__ alpha_s, float* __restrict__ alpha_d,
        const int* __restrict__ flag) {
    __shared__ unsigned short Wh[HID * HID];   // 32 KB swizzled W-hi image
    const int t = threadIdx.x;
    const int base = blockIdx.x * 64;
    const int hf = *flag;
    const unsigned short* Wlo = Wb + HID * HID;

    // stage W-hi: linear 32-KB copy (swizzle already baked into Wb)
#pragma unroll
    for (int i = 0; i < 8; ++i) {
        int c = i * 256 + t;                  // 16-B chunk id, 2048 total
        ((short8v*)Wh)[c] = ((const short8v*)Wb)[c];
    }
    __syncthreads();

    const int w  = t >> 6;
    const int l  = t & 63;
    const int lr = l & 15;    // A row / B,D col within 16
    const int lk = l >> 4;    // quarter: k sub-block
    const int arow = base + w * 16 + lr;
    const bool rowok = (arow < NN);

    // ---- A fragments for all 4 k-slices, straight from global ----
    const short8v zv = (short8v){0, 0, 0, 0, 0, 0, 0, 0};
    short8v ahi[4], alo[4];
    if (hf) {
        const unsigned short* hp = (const unsigned short*)h_ + (size_t)arow * HID + lk * 8;
#pragma unroll
        for (int ks = 0; ks < 4; ++ks) {
            ahi[ks] = rowok ? *(const short8v*)(hp + ks * 32) : zv;
            alo[ks] = zv;
        }
    } else {
        const float* hp = (const float*)h_ + (size_t)arow * HID + lk * 8;
#pragma unroll
        for (int ks = 0; ks < 4; ++ks) {
            float4 v0 = make_float4(0.f, 0.f, 0.f, 0.f), v1 = v0;
            if (rowok) {
                v0 = *(const float4*)(hp + ks * 32);
                v1 = *(const float4*)(hp + ks * 32 + 4);
            }
            ushort4 h0, l0, h1, l1;
            splitbf(v0.x, h0.x, l0.x); splitbf(v0.y, h0.y, l0.y);
            splitbf(v0.z, h0.z, l0.z); splitbf(v0.w, h0.w, l0.w);
            splitbf(v1.x, h1.x, l1.x); splitbf(v1.y, h1.y, l1.y);
            splitbf(v1.z, h1.z, l1.z); splitbf(v1.w, h1.w, l1.w);
            ahi[ks] = (short8v){(short)h0.x, (short)h0.y, (short)h0.z, (short)h0.w,
                                (short)h1.x, (short)h1.y, (short)h1.z, (short)h1.w};
            alo[ks] = (short8v){(short)l0.x, (short)l0.y, (short)l0.z, (short)l0.w,
                                (short)l1.x, (short)l1.y, (short)l1.z, (short)l1.w};
        }
    }

    // ---- MFMA main ----
    f32x4 acc[8];
#pragma unroll
    for (int nt = 0; nt < 8; ++nt) acc[nt] = (f32x4){0.f, 0.f, 0.f, 0.f};

    if (hf) {
#pragma unroll
        for (int ks = 0; ks < 4; ++ks) {
#pragma unroll
            for (int nt = 0; nt < 8; ++nt) {
                int row = nt * 16 + lr;
                int bo = (row * 256 + ks * 64 + lk * 16) ^ ((lr & 7) << 4);
                short8v bhi = *(const short8v*)((const char*)Wh + bo);
                short8v blo = *(const short8v*)(Wlo + row * HID + ks * 32 + lk * 8);
                acc[nt] = __builtin_amdgcn_mfma_f32_16x16x32_bf16(ahi[ks], bhi, acc[nt], 0, 0, 0);
                acc[nt] = __builtin_amdgcn_mfma_f32_16x16x32_bf16(ahi[ks], blo, acc[nt], 0, 0, 0);
            }
        }
    } else {
#pragma unroll
        for (int ks = 0; ks < 4; ++ks) {
#pragma unroll
            for (int nt = 0; nt < 8; ++nt) {
                int row = nt * 16 + lr;
                int bo = (row * 256 + ks * 64 + lk * 16) ^ ((lr & 7) << 4);
                short8v bhi = *(const short8v*)((const char*)Wh + bo);
                short8v blo = *(const short8v*)(Wlo + row * HID + ks * 32 + lk * 8);
                acc[nt] = __builtin_amdgcn_mfma_f32_16x16x32_bf16(ahi[ks], bhi, acc[nt], 0, 0, 0);
                acc[nt] = __builtin_amdgcn_mfma_f32_16x16x32_bf16(alo[ks], bhi, acc[nt], 0, 0, 0);
                acc[nt] = __builtin_amdgcn_mfma_f32_16x16x32_bf16(ahi[ks], blo, acc[nt], 0, 0, 0);
            }
        }
    }

    // ---- epilogue: alpha logits from fp32 acc, then bf16 x store ----
    float ps[4] = {0.f, 0.f, 0.f, 0.f};
    float pd[4] = {0.f, 0.f, 0.f, 0.f};
#pragma unroll
    for (int nt = 0; nt < 8; ++nt) {
        float asv = a_s[nt * 16 + lr];
        float adv = a_d[nt * 16 + lr];
#pragma unroll
        for (int r = 0; r < 4; ++r) {
            ps[r] = fmaf(acc[nt][r], asv, ps[r]);
            pd[r] = fmaf(acc[nt][r], adv, pd[r]);
        }
    }
#pragma unroll
    for (int m = 8; m >= 1; m >>= 1) {
#pragma unroll
        for (int r = 0; r < 4; ++r) {
            ps[r] += __shfl_xor(ps[r], m, 16);   // reduce across the 16 col-lanes
            pd[r] += __shfl_xor(pd[r], m, 16);
        }
    }
#pragma unroll
    for (int r = 0; r < 4; ++r) {
        int grow = base + w * 16 + lk * 4 + r;
        if (grow < NN) {
#pragma unroll
            for (int nt = 0; nt < 8; ++nt)
                x[(size_t)grow * HID + nt * 16 + lr] = f2b(acc[nt][r]);
            if (lr == 0) { alpha_s[grow] = ps[r]; alpha_d[grow] = pd[r]; }
        }
    }
}

// ---------- fused softmax + weighted aggregation ----------
__global__ __launch_bounds__(256) void aggregate_fused(
        const unsigned short* __restrict__ x, const int* __restrict__ deg_,
        const int* __restrict__ csr, const float* __restrict__ als,
        const float* __restrict__ ald, const float* __restrict__ bias,
        void* __restrict__ out, const int* __restrict__ flag, int do_relu) {
    int node = (blockIdx.x * 256 + threadIdx.x) >> 6;
    int lane = threadIdx.x & 63;
    if (node >= NN) return;
    int deg = min(deg_[node], CAP);
    const int* list = csr + (node << 6);
    const unsigned int* x2 = (const unsigned int*)x;   // ushort2 as u32
    float adv = ald[node];
    float accx = 0.f, accy = 0.f, den = 0.f;
    for (int j0 = 0; j0 < deg; j0 += 8) {
        int idx[8];
#pragma unroll
        for (int k = 0; k < 8; ++k) {
            int j = j0 + k;
            idx[k] = list[j < deg ? j : j0];
        }
        float e8[8];
#pragma unroll
        for (int k = 0; k < 8; ++k) e8[k] = als[idx[k]];        // broadcast gather
        unsigned int u[8];
#pragma unroll
        for (int k = 0; k < 8; ++k) u[k] = x2[(size_t)idx[k] * 64 + lane];
#pragma unroll
        for (int k = 0; k < 8; ++k) {
            float e = e8[k] + adv;
            e = fmaxf(e, NEG_SLOPE * e);             // leaky_relu
            e = fminf(e, 60.f);                      // inf hardening
            float p = (j0 + k < deg) ? __expf(e) : 0.f;
            den += p;
            accx = fmaf(p, b2f((unsigned short)(u[k] & 0xFFFFu)), accx);
            accy = fmaf(p, b2f((unsigned short)(u[k] >> 16)), accy);
        }
    }
    float inv = 1.f / (den + 1e-16f);
    float2 bv = ((const float2*)bias)[lane];
    float ox = accx * inv + bv.x;
    float oy = accy * inv + bv.y;
    if (do_relu) { ox = fmaxf(ox, 0.f); oy = fmaxf(oy, 0.f); }
    if (*flag) {
        ushort2 pk; pk.x = f2b(ox); pk.y = f2b(oy);
        *(ushort2*)((unsigned short*)out + node * HID + lane * 2) = pk;
    } else {
        ((float2*)out)[node * 64 + lane] = make_float2(ox, oy);
    }
}

extern "C" void kernel_launch(void* const* d_in, const int* in_sizes, int n_in,
                              void* d_out, int out_size, void* d_ws, size_t ws_size,
                              hipStream_t stream) {
    const void* z_in  = d_in[0];
    const int*  ei    = (const int*)d_in[1];
    const void* Ws_in = d_in[2];
    const void* as_in = d_in[3];
    const void* ad_in = d_in[4];
    const void* b_in  = d_in[5];

    char* wsp = (char*)d_ws;
    auto alloc = [&](size_t bytes) -> char* {
        char* p = wsp; wsp += (bytes + 255) & ~(size_t)255; return p;
    };
    int*            dflag   = (int*)alloc(4);
    int*            pos     = (int*)alloc(NN * 4);               // degree array
    int*            csrp    = (int*)alloc((size_t)NN * CAP * 4); // padded CSR (12.8 MB)
    float*          alpha_s = (float*)alloc(NN * 4);
    float*          alpha_d = (float*)alloc(NN * 4);
    unsigned short* Wb      = (unsigned short*)alloc((size_t)3 * 2 * HID * HID * 2); // hi(swz)+lo W
    float*          asf     = (float*)alloc(3 * HID * 4);
    float*          adf     = (float*)alloc(3 * HID * 4);
    float*          bff     = (float*)alloc(3 * HID * 4);
    unsigned short* xb      = (unsigned short*)alloc((size_t)NN * HID * 2);  // bf16 x

    // dtype probe first — everything downstream branches on *dflag
    probe_dtype<<<1, 64, 0, stream>>>((const unsigned short*)z_in, dflag);

    // params: W -> split hi(swizzled)/lo fragment layout; vectors -> f32
    wprep<<<(3 * HID * HID + 255) / 256, 256, 0, stream>>>(Ws_in, Wb, dflag);
    cvt3<<<5, 256, 0, stream>>>(as_in, ad_in, b_in, asf, adf, bff, dflag);

    // padded CSR build: memset degrees + single swizzled scatter pass
    hipMemsetAsync(pos, 0, NN * 4, stream);
    const int chunks = (ET + SCHUNK - 1) / SCHUNK;
    scatter_padded<<<chunks * 8, 256, 0, stream>>>(ei, pos, csrp);

    const int gemm_blocks = (NN + 63) / 64;
    const int wave_blocks = (NN + 3) / 4;   // 4 waves (nodes) per 256-thread block
    const size_t WL = 2 * HID * HID;        // per-layer Wb stride (ushorts)

    // layer 0
    gemm_alpha<<<gemm_blocks, 256, 0, stream>>>(z_in, Wb, asf, adf, xb, alpha_s, alpha_d, dflag);
    aggregate_fused<<<wave_blocks, 256, 0, stream>>>(xb, pos, csrp, alpha_s, alpha_d, bff, d_out, dflag, 1);

    // layer 1 (d_out ping-pong: aggregate reads only xb/als/csr — overwrite safe)
    gemm_alpha<<<gemm_blocks, 256, 0, stream>>>(d_out, Wb + WL, asf + HID, adf + HID,
                                                xb, alpha_s, alpha_d, dflag);
    aggregate_fused<<<wave_blocks, 256, 0, stream>>>(xb, pos, csrp, alpha_s, alpha_d, bff + HID, d_out, dflag, 1);

    // layer 2 (final, no relu)
    gemm_alpha<<<gemm_blocks, 256, 0, stream>>>(d_out, Wb + 2 * WL, asf + 2 * HID,
                                                adf + 2 * HID, xb, alpha_s, alpha_d, dflag);
    aggregate_fused<<<wave_blocks, 256, 0, stream>>>(xb, pos, csrp, alpha_s, alpha_d, bff + 2 * HID, d_out, dflag, 0);
}